// Round 5
// baseline (79.304 us; speedup 1.0000x reference)
//
#include <hip/hip_runtime.h>
#include <math.h>

#define B_ 4
#define T_ 64
#define D_ 8
#define V_ 2000
#define LOG2PI_F 1.8378770664093453f
#define CHUNK 16
#define TDONE 16  /* flags[16] = table-done counter */

#define RCP(x) __builtin_amdgcn_rcpf(x)

__device__ __forceinline__ float rdl(float v, int lane) {
  return __int_as_float(__builtin_amdgcn_readlane(__float_as_int(v), lane));
}

// Cholesky of (A + diag(dadd)) with A read from LDS (block-shared, broadcast
// reads -> saves 64 VGPRs/thread). Returns |L^{-1} eta|^2 and logdet.
__device__ __forceinline__ float chol_quad_lds(const float* sA, const float dadd[D_],
                                               const float eta[D_], float& logdet) {
  float L[D_][D_];
  float rs[D_];
  float p0 = 1.f, p1 = 1.f;
#pragma unroll
  for (int j = 0; j < D_; ++j) {
    float c = sA[j * 8 + j] + dadd[j];
#pragma unroll
    for (int k = 0; k < D_; ++k) {
      if (k < j) c -= L[j][k] * L[j][k];
    }
    if (j < 4) p0 *= c; else p1 *= c;
    float r = rsqrtf(c);
    rs[j] = r;
#pragma unroll
    for (int i = 0; i < D_; ++i) {
      if (i > j) {
        float s = sA[i * 8 + j];
#pragma unroll
        for (int k = 0; k < D_; ++k) {
          if (k < j) s -= L[i][k] * L[j][k];
        }
        L[i][j] = s * r;
      }
    }
  }
  logdet = __logf(p0) + __logf(p1);
  float z[D_];
  float q = 0.f;
#pragma unroll
  for (int i = 0; i < D_; ++i) {
    float s = eta[i];
#pragma unroll
    for (int k = 0; k < D_; ++k) {
      if (k < i) s -= L[i][k] * z[k];
    }
    z[i] = s * rs[i];
    q = fmaf(z[i], z[i], q);
  }
  return q;
}

// Fused kernel, 520 co-resident blocks:
//   blocks 0..3    : per-batch scan (R4-verified hot loop), publishes every
//                    CHUNK steps via threadfence + device atomic flag
//   blocks 4..7    : decoder table (500 words each) + table-done flag
//   blocks 8..519  : consumers: spin on (chunk flag, table flag), then phase_b
extern "C" __global__ void __launch_bounds__(256)
k_fused(const int* __restrict__ sent, const float* __restrict__ em_mu,
        const float* __restrict__ em_cho, const float* __restrict__ tr_mu,
        const float* __restrict__ tr_cho, const float* __restrict__ dec_mu,
        const float* __restrict__ dec_cho, float* __restrict__ lam0_ws,
        float* __restrict__ eta0_ws, float* __restrict__ table,
        int* __restrict__ flags, float* __restrict__ out) {
  const int bid = blockIdx.x;
  const int tid = threadIdx.x;

  if (bid < B_) {
    // ================= scan block =================
    __shared__ float sC[16][16], sCi[16][16], sLt[16][16];
    __shared__ float sEt[16], sMu[16];
    __shared__ float sLamW[T_][8], sWmuT[T_][8];
    const int b = bid;

    // stage all word data (lanes 0..63 of wave 0)
    int sw = 0;
    if (tid < 64) {
      sw = sent[b * T_ + tid];
      const float4* pc = (const float4*)(em_cho + sw * D_);
      const float4* pm = (const float4*)(em_mu + sw * D_);
      float4 c0 = pc[0], c1 = pc[1];
      float4 m0 = pm[0], m1 = pm[1];
      sLamW[tid][0] = RCP(c0.x * c0.x);
      sLamW[tid][1] = RCP(c0.y * c0.y);
      sLamW[tid][2] = RCP(c0.z * c0.z);
      sLamW[tid][3] = RCP(c0.w * c0.w);
      sLamW[tid][4] = RCP(c1.x * c1.x);
      sLamW[tid][5] = RCP(c1.y * c1.y);
      sLamW[tid][6] = RCP(c1.z * c1.z);
      sLamW[tid][7] = RCP(c1.w * c1.w);
      sWmuT[tid][0] = m0.x; sWmuT[tid][1] = m0.y;
      sWmuT[tid][2] = m0.z; sWmuT[tid][3] = m0.w;
      sWmuT[tid][4] = m1.x; sWmuT[tid][5] = m1.y;
      sWmuT[tid][6] = m1.z; sWmuT[tid][7] = m1.w;
    }

    // preamble: lam_t = inv(C^T C), eta_t = lam_t @ mu (256 threads)
    sC[tid >> 4][tid & 15] = tr_cho[tid];
    if (tid < 16) sMu[tid] = tr_mu[tid];
    __syncthreads();
    if (tid < 16) {
      const int j = tid;
      float col[16];
#pragma unroll
      for (int i = 0; i < 16; ++i) {
        float s = (i == j) ? 1.f : 0.f;
#pragma unroll
        for (int k = 0; k < 16; ++k) {
          if (k < i) s = fmaf(-sC[i][k], col[k], s);
        }
        col[i] = s * RCP(sC[i][i]);
      }
#pragma unroll
      for (int i = 0; i < 16; ++i) sCi[i][j] = col[i];
    }
    __syncthreads();
    {
      int i = tid >> 4, jq = tid & 15;
      float s = 0.f;
#pragma unroll
      for (int k = 0; k < 16; ++k) s = fmaf(sCi[i][k], sCi[jq][k], s);
      sLt[i][jq] = s;
    }
    __syncthreads();
    if (tid < 16) {
      float s = 0.f;
#pragma unroll
      for (int k = 0; k < 16; ++k) s = fmaf(sLt[tid][k], sMu[k], s);
      sEt[tid] = s;
    }
    __syncthreads();
    if (tid >= 64) return;  // no further barriers: wave 0 only

    // row-per-lane register state: lane i holds row i
    const int i = tid & 7;
    float ltAA[8], ltAB[8], ltBA[8], ltBB[8];
#pragma unroll
    for (int j = 0; j < 8; ++j) {
      ltAA[j] = sLt[i][j];
      ltAB[j] = sLt[i][8 + j];
      ltBA[j] = sLt[8 + i][j];
      ltBB[j] = sLt[8 + i][8 + j];
    }
    const float etH = sEt[i], etT = sEt[8 + i];

    float lam[8];
#pragma unroll
    for (int j = 0; j < 8; ++j) lam[j] = (j == i) ? 1.f : 0.f;
    float eta = 0.f;

    float* lamOut = lam0_ws + b * T_ * 64;
    float* etaOut = eta0_ws + b * T_ * 8;

    float lamw = sLamW[0][i];
    float wmu = sWmuT[0][i];

#pragma unroll 1
    for (int t = 0; t < T_; ++t) {
      float lamw_n = sLamW[(t + 1) & (T_ - 1)][i];
      float wmu_n = sWmuT[(t + 1) & (T_ - 1)][i];

      float A[8], Bm[8], Cr[8], Dm[8];
#pragma unroll
      for (int j = 0; j < 8; ++j) A[j] = ltAA[j] + lam[j];
      float ev = etH + eta;
      float et = etT;

      // iter 0 (B/C/D sourced from lt registers)
      {
        float srA[8], srB[8];
#pragma unroll
        for (int j = 0; j < 8; ++j) srA[j] = rdl(A[j], 0);
#pragma unroll
        for (int j = 0; j < 8; ++j) srB[j] = rdl(ltAB[j], 0);
        float srE = rdl(ev, 0);
        float rp = RCP(srA[0]);
        float f1 = (i == 0) ? 0.f : A[0] * rp;
        float f2 = ltBA[0] * rp;
#pragma unroll
        for (int j = 1; j < 8; ++j) {
          A[j] = fmaf(-f1, srA[j], A[j]);
          Cr[j] = fmaf(-f2, srA[j], ltBA[j]);
        }
#pragma unroll
        for (int j = 0; j < 8; ++j) {
          Bm[j] = fmaf(-f1, srB[j], ltAB[j]);
          Dm[j] = fmaf(-f2, srB[j], ltBB[j]);
        }
        ev = fmaf(-f1, srE, ev);
        et = fmaf(-f2, srE, et);
      }
      // iters 1..7
#pragma unroll
      for (int k = 1; k < 8; ++k) {
        float srA[8], srB[8];
#pragma unroll
        for (int j = 0; j < 8; ++j) {
          if (j >= k) srA[j] = rdl(A[j], k);
        }
#pragma unroll
        for (int j = 0; j < 8; ++j) srB[j] = rdl(Bm[j], k);
        float srE = rdl(ev, k);
        float rp = RCP(srA[k]);
        float f1 = (i == k) ? 0.f : A[k] * rp;
        float f2 = Cr[k] * rp;
#pragma unroll
        for (int j = k + 1; j < 8; ++j) {
          A[j] = fmaf(-f1, srA[j], A[j]);
          Cr[j] = fmaf(-f2, srA[j], Cr[j]);
        }
#pragma unroll
        for (int j = 0; j < 8; ++j) {
          Bm[j] = fmaf(-f1, srB[j], Bm[j]);
          Dm[j] = fmaf(-f2, srB[j], Dm[j]);
        }
        ev = fmaf(-f1, srE, ev);
        et = fmaf(-f2, srE, et);
      }

      // epilogue
#pragma unroll
      for (int j = 0; j < 8; ++j) lam[j] = (j == i) ? Dm[j] + lamw : Dm[j];
      eta = fmaf(lamw, wmu, et);

      if (tid < 8) {
        float4* dst = (float4*)(lamOut + t * 64 + i * 8);
        dst[0] = make_float4(lam[0], lam[1], lam[2], lam[3]);
        dst[1] = make_float4(lam[4], lam[5], lam[6], lam[7]);
        etaOut[t * 8 + i] = eta;
      }
      // publish finished chunk (release: fence then device atomic)
      if ((t & (CHUNK - 1)) == (CHUNK - 1)) {
        __threadfence();
        if (tid == 0) atomicExch(&flags[b * (T_ / CHUNK) + (t >> 4)], 1);
      }
      lamw = lamw_n;
      wmu = wmu_n;
    }
    return;
  }

  if (bid < B_ + 4) {
    // ================= table block =================
    const int v0 = (bid - B_) * 500;
#pragma unroll
    for (int it = 0; it < 2; ++it) {
      int off = it * 256 + tid;
      if (off < 500) {
        int v = v0 + off;
        float sl = 0.f, q = 0.f;
#pragma unroll
        for (int j = 0; j < D_; ++j) {
          float c = dec_cho[v * D_ + j];
          float m = dec_mu[v * D_ + j];
          float l = 1.f / (c * c);
          float e = m * l;
          sl += __logf(l);
          q = fmaf(e, m, q);
          table[j * V_ + v] = l;
          table[(D_ + j) * V_ + v] = e;
        }
        table[16 * V_ + v] = -0.5f * (8.f * LOG2PI_F - sl + q);
      }
    }
    __threadfence();   // each thread drains+flushes its own stores
    __syncthreads();
    if (tid == 0) atomicAdd(&flags[TDONE], 1);
    return;
  }

  // ================= consumer block =================
  {
    const int cid = bid - B_ - 4;          // 0..511
    const int bt = cid >> 1;               // 0..255  (= b*64 + t)
    const int half = cid & 1;
    const int fi = (bt >> 6) * (T_ / CHUNK) + ((bt & 63) >> 4);

    if (tid == 0) {
      while (atomicAdd(&flags[fi], 0) == 0) __builtin_amdgcn_s_sleep(8);
      while (atomicAdd(&flags[TDONE], 0) < 4) __builtin_amdgcn_s_sleep(8);
      __threadfence();  // acquire: invalidate caches before data reads
    }
    __syncthreads();

    __shared__ float sL[64];
    __shared__ float sE[8];
    if (tid < 64) sL[tid] = lam0_ws[bt * 64 + tid];
    if (tid < 8) sE[tid] = eta0_ws[bt * 8 + tid];
    __syncthreads();

    float e0[D_];
#pragma unroll
    for (int ii = 0; ii < D_; ++ii) e0[ii] = sE[ii];
    float zero[D_];
#pragma unroll
    for (int j = 0; j < D_; ++j) zero[j] = 0.f;
    float ld0;
    float q0 = chol_quad_lds(sL, zero, e0, ld0);
    const float zeta0 = -0.5f * (8.f * LOG2PI_F - ld0 + q0);

#pragma unroll 1
    for (int it = 0; it < 4; ++it) {
      int off = it * 256 + tid;
      if (off < 1000) {
        int v = half * 1000 + off;
        float dl[D_], ef[D_];
#pragma unroll
        for (int j = 0; j < D_; ++j) {
          dl[j] = table[j * V_ + v];
          ef[j] = e0[j] + table[(D_ + j) * V_ + v];
        }
        float z1 = table[16 * V_ + v];
        float ldn;
        float qn = chol_quad_lds(sL, dl, ef, ldn);
        float zeta_n = -0.5f * (8.f * LOG2PI_F - ldn + qn);
        out[bt * V_ + v] = zeta0 + z1 - zeta_n;
      }
    }
  }
}

extern "C" void kernel_launch(void* const* d_in, const int* in_sizes, int n_in,
                              void* d_out, int out_size, void* d_ws, size_t ws_size,
                              hipStream_t stream) {
  const int* sent = (const int*)d_in[0];
  const float* em_mu = (const float*)d_in[2];
  const float* em_cho = (const float*)d_in[3];
  const float* tr_mu = (const float*)d_in[4];
  const float* tr_cho = (const float*)d_in[5];
  const float* dec_mu = (const float*)d_in[6];
  const float* dec_cho = (const float*)d_in[7];
  float* out = (float*)d_out;

  float* ws = (float*)d_ws;
  float* lam0_ws = ws;                        // 4*64*64 = 16384 floats
  float* eta0_ws = ws + 16384;                // 2048 floats
  float* table = ws + 16384 + 2048;           // 34000 floats
  int* flags = (int*)(ws + 16384 + 2048 + 34000);  // 32 ints

  hipMemsetAsync(flags, 0, 32 * sizeof(int), stream);
  k_fused<<<dim3(B_ + 4 + 512), dim3(256), 0, stream>>>(
      sent, em_mu, em_cho, tr_mu, tr_cho, dec_mu, dec_cho,
      lam0_ws, eta0_ws, table, flags, out);
}

// Round 6
// 79.261 us; speedup vs baseline: 1.0005x; 1.0005x over previous
//
#include <hip/hip_runtime.h>
#include <math.h>

#define B_ 4
#define T_ 64
#define D_ 8
#define V_ 2000
#define LOG2PI_F 1.8378770664093453f
#define CHUNK 16
#define TDONE 16  /* flags[16] = table-done counter */

#define RCP(x) __builtin_amdgcn_rcpf(x)

__device__ __forceinline__ float rdl(float v, int lane) {
  return __int_as_float(__builtin_amdgcn_readlane(__float_as_int(v), lane));
}

// Cholesky of (A + diag(dadd)) with A read from LDS (block-shared, broadcast
// reads -> saves 64 VGPRs/thread). Returns |L^{-1} eta|^2 and logdet.
__device__ __forceinline__ float chol_quad_lds(const float* sA, const float dadd[D_],
                                               const float eta[D_], float& logdet) {
  float L[D_][D_];
  float rs[D_];
  float p0 = 1.f, p1 = 1.f;
#pragma unroll
  for (int j = 0; j < D_; ++j) {
    float c = sA[j * 8 + j] + dadd[j];
#pragma unroll
    for (int k = 0; k < D_; ++k) {
      if (k < j) c -= L[j][k] * L[j][k];
    }
    if (j < 4) p0 *= c; else p1 *= c;
    float r = rsqrtf(c);
    rs[j] = r;
#pragma unroll
    for (int i = 0; i < D_; ++i) {
      if (i > j) {
        float s = sA[i * 8 + j];
#pragma unroll
        for (int k = 0; k < D_; ++k) {
          if (k < j) s -= L[i][k] * L[j][k];
        }
        L[i][j] = s * r;
      }
    }
  }
  logdet = __logf(p0) + __logf(p1);
  float z[D_];
  float q = 0.f;
#pragma unroll
  for (int i = 0; i < D_; ++i) {
    float s = eta[i];
#pragma unroll
    for (int k = 0; k < D_; ++k) {
      if (k < i) s -= L[i][k] * z[k];
    }
    z[i] = s * rs[i];
    q = fmaf(z[i], z[i], q);
  }
  return q;
}

// Fused kernel, 520 co-resident blocks:
//   blocks 0..3    : per-batch scan (R4-verified hot loop), publishes every
//                    CHUNK steps via threadfence + device atomic flag
//   blocks 4..7    : decoder table (500 words each) + table-done flag
//   blocks 8..519  : consumers: spin on (chunk flag, table flag), then phase_b
extern "C" __global__ void __launch_bounds__(256)
k_fused(const int* __restrict__ sent, const float* __restrict__ em_mu,
        const float* __restrict__ em_cho, const float* __restrict__ tr_mu,
        const float* __restrict__ tr_cho, const float* __restrict__ dec_mu,
        const float* __restrict__ dec_cho, float* __restrict__ lam0_ws,
        float* __restrict__ eta0_ws, float* __restrict__ table,
        int* __restrict__ flags, float* __restrict__ out) {
  const int bid = blockIdx.x;
  const int tid = threadIdx.x;

  if (bid < B_) {
    // ================= scan block =================
    __shared__ float sC[16][16], sCi[16][16], sLt[16][16];
    __shared__ float sEt[16], sMu[16];
    __shared__ float sLamW[T_][8], sWmuT[T_][8];
    const int b = bid;

    // stage all word data (lanes 0..63 of wave 0)
    int sw = 0;
    if (tid < 64) {
      sw = sent[b * T_ + tid];
      const float4* pc = (const float4*)(em_cho + sw * D_);
      const float4* pm = (const float4*)(em_mu + sw * D_);
      float4 c0 = pc[0], c1 = pc[1];
      float4 m0 = pm[0], m1 = pm[1];
      sLamW[tid][0] = RCP(c0.x * c0.x);
      sLamW[tid][1] = RCP(c0.y * c0.y);
      sLamW[tid][2] = RCP(c0.z * c0.z);
      sLamW[tid][3] = RCP(c0.w * c0.w);
      sLamW[tid][4] = RCP(c1.x * c1.x);
      sLamW[tid][5] = RCP(c1.y * c1.y);
      sLamW[tid][6] = RCP(c1.z * c1.z);
      sLamW[tid][7] = RCP(c1.w * c1.w);
      sWmuT[tid][0] = m0.x; sWmuT[tid][1] = m0.y;
      sWmuT[tid][2] = m0.z; sWmuT[tid][3] = m0.w;
      sWmuT[tid][4] = m1.x; sWmuT[tid][5] = m1.y;
      sWmuT[tid][6] = m1.z; sWmuT[tid][7] = m1.w;
    }

    // preamble: lam_t = inv(C^T C), eta_t = lam_t @ mu (256 threads)
    sC[tid >> 4][tid & 15] = tr_cho[tid];
    if (tid < 16) sMu[tid] = tr_mu[tid];
    __syncthreads();
    if (tid < 16) {
      const int j = tid;
      float col[16];
#pragma unroll
      for (int i = 0; i < 16; ++i) {
        float s = (i == j) ? 1.f : 0.f;
#pragma unroll
        for (int k = 0; k < 16; ++k) {
          if (k < i) s = fmaf(-sC[i][k], col[k], s);
        }
        col[i] = s * RCP(sC[i][i]);
      }
#pragma unroll
      for (int i = 0; i < 16; ++i) sCi[i][j] = col[i];
    }
    __syncthreads();
    {
      int i = tid >> 4, jq = tid & 15;
      float s = 0.f;
#pragma unroll
      for (int k = 0; k < 16; ++k) s = fmaf(sCi[i][k], sCi[jq][k], s);
      sLt[i][jq] = s;
    }
    __syncthreads();
    if (tid < 16) {
      float s = 0.f;
#pragma unroll
      for (int k = 0; k < 16; ++k) s = fmaf(sLt[tid][k], sMu[k], s);
      sEt[tid] = s;
    }
    __syncthreads();
    if (tid >= 64) return;  // no further barriers: wave 0 only

    // row-per-lane register state: lane i holds row i
    const int i = tid & 7;
    float ltAA[8], ltAB[8], ltBA[8], ltBB[8];
#pragma unroll
    for (int j = 0; j < 8; ++j) {
      ltAA[j] = sLt[i][j];
      ltAB[j] = sLt[i][8 + j];
      ltBA[j] = sLt[8 + i][j];
      ltBB[j] = sLt[8 + i][8 + j];
    }
    const float etH = sEt[i], etT = sEt[8 + i];

    float lam[8];
#pragma unroll
    for (int j = 0; j < 8; ++j) lam[j] = (j == i) ? 1.f : 0.f;
    float eta = 0.f;

    float* lamOut = lam0_ws + b * T_ * 64;
    float* etaOut = eta0_ws + b * T_ * 8;

    float lamw = sLamW[0][i];
    float wmu = sWmuT[0][i];

#pragma unroll 1
    for (int t = 0; t < T_; ++t) {
      float lamw_n = sLamW[(t + 1) & (T_ - 1)][i];
      float wmu_n = sWmuT[(t + 1) & (T_ - 1)][i];

      float A[8], Bm[8], Cr[8], Dm[8];
#pragma unroll
      for (int j = 0; j < 8; ++j) A[j] = ltAA[j] + lam[j];
      float ev = etH + eta;
      float et = etT;

      // iter 0 (B/C/D sourced from lt registers)
      {
        float srA[8], srB[8];
#pragma unroll
        for (int j = 0; j < 8; ++j) srA[j] = rdl(A[j], 0);
#pragma unroll
        for (int j = 0; j < 8; ++j) srB[j] = rdl(ltAB[j], 0);
        float srE = rdl(ev, 0);
        float rp = RCP(srA[0]);
        float f1 = (i == 0) ? 0.f : A[0] * rp;
        float f2 = ltBA[0] * rp;
#pragma unroll
        for (int j = 1; j < 8; ++j) {
          A[j] = fmaf(-f1, srA[j], A[j]);
          Cr[j] = fmaf(-f2, srA[j], ltBA[j]);
        }
#pragma unroll
        for (int j = 0; j < 8; ++j) {
          Bm[j] = fmaf(-f1, srB[j], ltAB[j]);
          Dm[j] = fmaf(-f2, srB[j], ltBB[j]);
        }
        ev = fmaf(-f1, srE, ev);
        et = fmaf(-f2, srE, et);
      }
      // iters 1..7
#pragma unroll
      for (int k = 1; k < 8; ++k) {
        float srA[8], srB[8];
#pragma unroll
        for (int j = 0; j < 8; ++j) {
          if (j >= k) srA[j] = rdl(A[j], k);
        }
#pragma unroll
        for (int j = 0; j < 8; ++j) srB[j] = rdl(Bm[j], k);
        float srE = rdl(ev, k);
        float rp = RCP(srA[k]);
        float f1 = (i == k) ? 0.f : A[k] * rp;
        float f2 = Cr[k] * rp;
#pragma unroll
        for (int j = k + 1; j < 8; ++j) {
          A[j] = fmaf(-f1, srA[j], A[j]);
          Cr[j] = fmaf(-f2, srA[j], Cr[j]);
        }
#pragma unroll
        for (int j = 0; j < 8; ++j) {
          Bm[j] = fmaf(-f1, srB[j], Bm[j]);
          Dm[j] = fmaf(-f2, srB[j], Dm[j]);
        }
        ev = fmaf(-f1, srE, ev);
        et = fmaf(-f2, srE, et);
      }

      // epilogue
#pragma unroll
      for (int j = 0; j < 8; ++j) lam[j] = (j == i) ? Dm[j] + lamw : Dm[j];
      eta = fmaf(lamw, wmu, et);

      if (tid < 8) {
        float4* dst = (float4*)(lamOut + t * 64 + i * 8);
        dst[0] = make_float4(lam[0], lam[1], lam[2], lam[3]);
        dst[1] = make_float4(lam[4], lam[5], lam[6], lam[7]);
        etaOut[t * 8 + i] = eta;
      }
      // publish finished chunk (release: fence then device atomic)
      if ((t & (CHUNK - 1)) == (CHUNK - 1)) {
        __threadfence();
        if (tid == 0) atomicExch(&flags[b * (T_ / CHUNK) + (t >> 4)], 1);
      }
      lamw = lamw_n;
      wmu = wmu_n;
    }
    return;
  }

  if (bid < B_ + 4) {
    // ================= table block =================
    const int v0 = (bid - B_) * 500;
#pragma unroll
    for (int it = 0; it < 2; ++it) {
      int off = it * 256 + tid;
      if (off < 500) {
        int v = v0 + off;
        float sl = 0.f, q = 0.f;
#pragma unroll
        for (int j = 0; j < D_; ++j) {
          float c = dec_cho[v * D_ + j];
          float m = dec_mu[v * D_ + j];
          float l = 1.f / (c * c);
          float e = m * l;
          sl += __logf(l);
          q = fmaf(e, m, q);
          table[j * V_ + v] = l;
          table[(D_ + j) * V_ + v] = e;
        }
        table[16 * V_ + v] = -0.5f * (8.f * LOG2PI_F - sl + q);
      }
    }
    __threadfence();   // each thread drains+flushes its own stores
    __syncthreads();
    if (tid == 0) atomicAdd(&flags[TDONE], 1);
    return;
  }

  // ================= consumer block =================
  {
    const int cid = bid - B_ - 4;          // 0..511
    const int bt = cid >> 1;               // 0..255  (= b*64 + t)
    const int half = cid & 1;
    const int fi = (bt >> 6) * (T_ / CHUNK) + ((bt & 63) >> 4);

    if (tid == 0) {
      while (atomicAdd(&flags[fi], 0) == 0) __builtin_amdgcn_s_sleep(8);
      while (atomicAdd(&flags[TDONE], 0) < 4) __builtin_amdgcn_s_sleep(8);
      __threadfence();  // acquire: invalidate caches before data reads
    }
    __syncthreads();

    __shared__ float sL[64];
    __shared__ float sE[8];
    if (tid < 64) sL[tid] = lam0_ws[bt * 64 + tid];
    if (tid < 8) sE[tid] = eta0_ws[bt * 8 + tid];
    __syncthreads();

    float e0[D_];
#pragma unroll
    for (int ii = 0; ii < D_; ++ii) e0[ii] = sE[ii];
    float zero[D_];
#pragma unroll
    for (int j = 0; j < D_; ++j) zero[j] = 0.f;
    float ld0;
    float q0 = chol_quad_lds(sL, zero, e0, ld0);
    const float zeta0 = -0.5f * (8.f * LOG2PI_F - ld0 + q0);

#pragma unroll 1
    for (int it = 0; it < 4; ++it) {
      int off = it * 256 + tid;
      if (off < 1000) {
        int v = half * 1000 + off;
        float dl[D_], ef[D_];
#pragma unroll
        for (int j = 0; j < D_; ++j) {
          dl[j] = table[j * V_ + v];
          ef[j] = e0[j] + table[(D_ + j) * V_ + v];
        }
        float z1 = table[16 * V_ + v];
        float ldn;
        float qn = chol_quad_lds(sL, dl, ef, ldn);
        float zeta_n = -0.5f * (8.f * LOG2PI_F - ldn + qn);
        out[bt * V_ + v] = zeta0 + z1 - zeta_n;
      }
    }
  }
}

extern "C" void kernel_launch(void* const* d_in, const int* in_sizes, int n_in,
                              void* d_out, int out_size, void* d_ws, size_t ws_size,
                              hipStream_t stream) {
  const int* sent = (const int*)d_in[0];
  const float* em_mu = (const float*)d_in[2];
  const float* em_cho = (const float*)d_in[3];
  const float* tr_mu = (const float*)d_in[4];
  const float* tr_cho = (const float*)d_in[5];
  const float* dec_mu = (const float*)d_in[6];
  const float* dec_cho = (const float*)d_in[7];
  float* out = (float*)d_out;

  float* ws = (float*)d_ws;
  float* lam0_ws = ws;                        // 4*64*64 = 16384 floats
  float* eta0_ws = ws + 16384;                // 2048 floats
  float* table = ws + 16384 + 2048;           // 34000 floats
  int* flags = (int*)(ws + 16384 + 2048 + 34000);  // 32 ints

  hipMemsetAsync(flags, 0, 32 * sizeof(int), stream);
  k_fused<<<dim3(B_ + 4 + 512), dim3(256), 0, stream>>>(
      sent, em_mu, em_cho, tr_mu, tr_cho, dec_mu, dec_cho,
      lam0_ws, eta0_ws, table, flags, out);
}

// Round 7
// 67.838 us; speedup vs baseline: 1.1690x; 1.1684x over previous
//
#include <hip/hip_runtime.h>
#include <math.h>

#define B_ 4
#define T_ 64
#define D_ 8
#define V_ 2000
#define LOG2PI_F 1.8378770664093453f
#define CHUNK 16
#define NCHUNK (T_ / CHUNK)
#define FLAG_STRIDE 32                 /* one flag per 128B line */
#define TDONE_IDX 16                   /* flags[16*32] = table-done counter */

#define RCP(x) __builtin_amdgcn_rcpf(x)

__device__ __forceinline__ float rdl(float v, int lane) {
  return __int_as_float(__builtin_amdgcn_readlane(__float_as_int(v), lane));
}

// Cholesky of (A + diag(dadd)) with A read from LDS (broadcast, saves VGPRs).
__device__ __forceinline__ float chol_quad_lds(const float* sA, const float dadd[D_],
                                               const float eta[D_], float& logdet) {
  float L[D_][D_];
  float rs[D_];
  float p0 = 1.f, p1 = 1.f;
#pragma unroll
  for (int j = 0; j < D_; ++j) {
    float c = sA[j * 8 + j] + dadd[j];
#pragma unroll
    for (int k = 0; k < D_; ++k) {
      if (k < j) c -= L[j][k] * L[j][k];
    }
    if (j < 4) p0 *= c; else p1 *= c;
    float r = rsqrtf(c);
    rs[j] = r;
#pragma unroll
    for (int i = 0; i < D_; ++i) {
      if (i > j) {
        float s = sA[i * 8 + j];
#pragma unroll
        for (int k = 0; k < D_; ++k) {
          if (k < j) s -= L[i][k] * L[j][k];
        }
        L[i][j] = s * r;
      }
    }
  }
  logdet = __logf(p0) + __logf(p1);
  float z[D_];
  float q = 0.f;
#pragma unroll
  for (int i = 0; i < D_; ++i) {
    float s = eta[i];
#pragma unroll
    for (int k = 0; k < D_; ++k) {
      if (k < i) s -= L[i][k] * z[k];
    }
    z[i] = s * rs[i];
    q = fmaf(z[i], z[i], q);
  }
  return q;
}

// Fused kernel, 520 blocks:
//  blocks 0..3   : per-batch scan; 2x2-block forward (Schur) elimination;
//                  publishes every CHUNK steps (fence + relaxed store, padded flag)
//  blocks 4..7   : decoder table + TDONE counter
//  blocks 8..519 : consumers; poll with relaxed atomic LOADS (no RMW) + s_sleep
extern "C" __global__ void __launch_bounds__(256)
k_fused(const int* __restrict__ sent, const float* __restrict__ em_mu,
        const float* __restrict__ em_cho, const float* __restrict__ tr_mu,
        const float* __restrict__ tr_cho, const float* __restrict__ dec_mu,
        const float* __restrict__ dec_cho, float* __restrict__ lam0_ws,
        float* __restrict__ eta0_ws, float* __restrict__ table,
        int* __restrict__ flags, float* __restrict__ out) {
  const int bid = blockIdx.x;
  const int tid = threadIdx.x;

  if (bid < B_) {
    // ================= scan block =================
    __shared__ float sC[16][16], sCi[16][16], sLt[16][16];
    __shared__ float sEt[16], sMu[16];
    __shared__ float sLamW[T_][8], sWmuT[T_][8];
    const int b = bid;

    if (tid < 64) {
      const int sw = sent[b * T_ + tid];
      const float4* pc = (const float4*)(em_cho + sw * D_);
      const float4* pm = (const float4*)(em_mu + sw * D_);
      float4 c0 = pc[0], c1 = pc[1];
      float4 m0 = pm[0], m1 = pm[1];
      sLamW[tid][0] = RCP(c0.x * c0.x);
      sLamW[tid][1] = RCP(c0.y * c0.y);
      sLamW[tid][2] = RCP(c0.z * c0.z);
      sLamW[tid][3] = RCP(c0.w * c0.w);
      sLamW[tid][4] = RCP(c1.x * c1.x);
      sLamW[tid][5] = RCP(c1.y * c1.y);
      sLamW[tid][6] = RCP(c1.z * c1.z);
      sLamW[tid][7] = RCP(c1.w * c1.w);
      sWmuT[tid][0] = m0.x; sWmuT[tid][1] = m0.y;
      sWmuT[tid][2] = m0.z; sWmuT[tid][3] = m0.w;
      sWmuT[tid][4] = m1.x; sWmuT[tid][5] = m1.y;
      sWmuT[tid][6] = m1.z; sWmuT[tid][7] = m1.w;
    }

    // preamble: lam_t = inv(C^T C), eta_t = lam_t @ mu
    sC[tid >> 4][tid & 15] = tr_cho[tid];
    if (tid < 16) sMu[tid] = tr_mu[tid];
    __syncthreads();
    if (tid < 16) {
      const int j = tid;
      float col[16];
#pragma unroll
      for (int i = 0; i < 16; ++i) {
        float s = (i == j) ? 1.f : 0.f;
#pragma unroll
        for (int k = 0; k < 16; ++k) {
          if (k < i) s = fmaf(-sC[i][k], col[k], s);
        }
        col[i] = s * RCP(sC[i][i]);
      }
#pragma unroll
      for (int i = 0; i < 16; ++i) sCi[i][j] = col[i];
    }
    __syncthreads();
    {
      int i = tid >> 4, jq = tid & 15;
      float s = 0.f;
#pragma unroll
      for (int k = 0; k < 16; ++k) s = fmaf(sCi[i][k], sCi[jq][k], s);
      sLt[i][jq] = s;
    }
    __syncthreads();
    if (tid < 16) {
      float s = 0.f;
#pragma unroll
      for (int k = 0; k < 16; ++k) s = fmaf(sLt[tid][k], sMu[k], s);
      sEt[tid] = s;
    }
    __syncthreads();
    if (tid >= 64) return;  // wave 0 only from here; no more barriers

    const int i = tid & 7;
    float ltAA[8], ltAB[8], ltBA[8], ltBB[8];
#pragma unroll
    for (int j = 0; j < 8; ++j) {
      ltAA[j] = sLt[i][j];
      ltAB[j] = sLt[i][8 + j];
      ltBA[j] = sLt[8 + i][j];
      ltBB[j] = sLt[8 + i][8 + j];
    }
    const float etH = sEt[i], etT = sEt[8 + i];

    float lam[8];
#pragma unroll
    for (int j = 0; j < 8; ++j) lam[j] = (j == i) ? 1.f : 0.f;
    float eta = 0.f;

    float* lamOut = lam0_ws + b * T_ * 64;
    float* etaOut = eta0_ws + b * T_ * 8;

    float lamw = sLamW[0][i];
    float wmu = sWmuT[0][i];

#pragma unroll 1
    for (int t = 0; t < T_; ++t) {
      float lamw_n = sLamW[(t + 1) & (T_ - 1)][i];
      float wmu_n = sWmuT[(t + 1) & (T_ - 1)][i];

      float A[8], Bm[8], Cr[8], Dm[8];
#pragma unroll
      for (int j = 0; j < 8; ++j) {
        A[j] = ltAA[j] + lam[j];
        Bm[j] = ltAB[j];
        Cr[j] = ltBA[j];
        Dm[j] = ltBB[j];
      }
      float ev = etH + eta;
      float et = etT;

      // 2x2-block forward elimination: 4 rounds, Schur lands in Dm/et.
#pragma unroll
      for (int kk = 0; kk < 8; kk += 2) {
        const int k1 = kk, k2 = kk + 1;
        float sA1[8], sA2[8], sB1[8], sB2[8];
#pragma unroll
        for (int j = 0; j < 8; ++j) {
          if (j >= k1) {
            sA1[j] = rdl(A[j], k1);
            sA2[j] = rdl(A[j], k2);
          }
        }
#pragma unroll
        for (int j = 0; j < 8; ++j) {
          sB1[j] = rdl(Bm[j], k1);
          sB2[j] = rdl(Bm[j], k2);
        }
        float sE1 = rdl(ev, k1), sE2 = rdl(ev, k2);
        float p11 = sA1[k1], p12 = sA1[k2];
        float p21 = sA2[k1], p22 = sA2[k2];
        float rdet = RCP(fmaf(p11, p22, -(p12 * p21)));
        float a1 = A[k1], a2 = A[k2];
        float g1 = (i > k2) ? (a1 * p22 - a2 * p21) * rdet : 0.f;
        float g2 = (i > k2) ? (a2 * p11 - a1 * p12) * rdet : 0.f;
        float c1 = Cr[k1], c2 = Cr[k2];
        float h1 = (c1 * p22 - c2 * p21) * rdet;
        float h2 = (c2 * p11 - c1 * p12) * rdet;
#pragma unroll
        for (int j = 0; j < 8; ++j) {
          if (j >= kk + 2) {
            A[j] = fmaf(-g1, sA1[j], fmaf(-g2, sA2[j], A[j]));
            Cr[j] = fmaf(-h1, sA1[j], fmaf(-h2, sA2[j], Cr[j]));
          }
        }
#pragma unroll
        for (int j = 0; j < 8; ++j) {
          Bm[j] = fmaf(-g1, sB1[j], fmaf(-g2, sB2[j], Bm[j]));
          Dm[j] = fmaf(-h1, sB1[j], fmaf(-h2, sB2[j], Dm[j]));
        }
        ev = fmaf(-g1, sE1, fmaf(-g2, sE2, ev));
        et = fmaf(-h1, sE1, fmaf(-h2, sE2, et));
      }

      // epilogue: lam2 = Schur + diag(lamw); eta2 = et + lamw*wmu
#pragma unroll
      for (int j = 0; j < 8; ++j) lam[j] = (j == i) ? Dm[j] + lamw : Dm[j];
      eta = fmaf(lamw, wmu, et);

      if (tid < 8) {
        float4* dst = (float4*)(lamOut + t * 64 + i * 8);
        dst[0] = make_float4(lam[0], lam[1], lam[2], lam[3]);
        dst[1] = make_float4(lam[4], lam[5], lam[6], lam[7]);
        etaOut[t * 8 + i] = eta;
      }
      if ((t & (CHUNK - 1)) == (CHUNK - 1)) {
        __threadfence();  // release: drain wave's stores to device scope
        if (tid == 0)
          __hip_atomic_store(&flags[(b * NCHUNK + (t >> 4)) * FLAG_STRIDE], 1,
                             __ATOMIC_RELAXED, __HIP_MEMORY_SCOPE_AGENT);
      }
      lamw = lamw_n;
      wmu = wmu_n;
    }
    return;
  }

  if (bid < B_ + 4) {
    // ================= table block =================
    const int v0 = (bid - B_) * 500;
#pragma unroll
    for (int it = 0; it < 2; ++it) {
      int off = it * 256 + tid;
      if (off < 500) {
        int v = v0 + off;
        float sl = 0.f, q = 0.f;
#pragma unroll
        for (int j = 0; j < D_; ++j) {
          float c = dec_cho[v * D_ + j];
          float m = dec_mu[v * D_ + j];
          float l = 1.f / (c * c);
          float e = m * l;
          sl += __logf(l);
          q = fmaf(e, m, q);
          table[j * V_ + v] = l;
          table[(D_ + j) * V_ + v] = e;
        }
        table[16 * V_ + v] = -0.5f * (8.f * LOG2PI_F - sl + q);
      }
    }
    __threadfence();
    __syncthreads();
    if (tid == 0) atomicAdd(&flags[TDONE_IDX * FLAG_STRIDE], 1);
    return;
  }

  // ================= consumer block =================
  {
    const int cid = bid - B_ - 4;          // 0..511
    const int bt = cid >> 1;               // 0..255  (= b*64 + t)
    const int half = cid & 1;
    const int fi = (bt >> 6) * NCHUNK + ((bt & 63) >> 4);

    if (tid == 0) {
      const int* fch = &flags[fi * FLAG_STRIDE];
      while (__hip_atomic_load(fch, __ATOMIC_RELAXED, __HIP_MEMORY_SCOPE_AGENT) == 0)
        __builtin_amdgcn_s_sleep(7);
      const int* ftd = &flags[TDONE_IDX * FLAG_STRIDE];
      while (__hip_atomic_load(ftd, __ATOMIC_RELAXED, __HIP_MEMORY_SCOPE_AGENT) < 4)
        __builtin_amdgcn_s_sleep(7);
      __threadfence();  // acquire
    }
    __syncthreads();

    __shared__ float sL[64];
    __shared__ float sE[8];
    if (tid < 64) sL[tid] = lam0_ws[bt * 64 + tid];
    if (tid < 8) sE[tid] = eta0_ws[bt * 8 + tid];
    __syncthreads();

    float e0[D_];
#pragma unroll
    for (int ii = 0; ii < D_; ++ii) e0[ii] = sE[ii];
    float zero[D_];
#pragma unroll
    for (int j = 0; j < D_; ++j) zero[j] = 0.f;
    float ld0;
    float q0 = chol_quad_lds(sL, zero, e0, ld0);
    const float zeta0 = -0.5f * (8.f * LOG2PI_F - ld0 + q0);

#pragma unroll 1
    for (int it = 0; it < 4; ++it) {
      int off = it * 256 + tid;
      if (off < 1000) {
        int v = half * 1000 + off;
        float dl[D_], ef[D_];
#pragma unroll
        for (int j = 0; j < D_; ++j) {
          dl[j] = table[j * V_ + v];
          ef[j] = e0[j] + table[(D_ + j) * V_ + v];
        }
        float z1 = table[16 * V_ + v];
        float ldn;
        float qn = chol_quad_lds(sL, dl, ef, ldn);
        float zeta_n = -0.5f * (8.f * LOG2PI_F - ldn + qn);
        out[bt * V_ + v] = zeta0 + z1 - zeta_n;
      }
    }
  }
}

extern "C" void kernel_launch(void* const* d_in, const int* in_sizes, int n_in,
                              void* d_out, int out_size, void* d_ws, size_t ws_size,
                              hipStream_t stream) {
  const int* sent = (const int*)d_in[0];
  const float* em_mu = (const float*)d_in[2];
  const float* em_cho = (const float*)d_in[3];
  const float* tr_mu = (const float*)d_in[4];
  const float* tr_cho = (const float*)d_in[5];
  const float* dec_mu = (const float*)d_in[6];
  const float* dec_cho = (const float*)d_in[7];
  float* out = (float*)d_out;

  float* ws = (float*)d_ws;
  float* lam0_ws = ws;                        // 16384 floats
  float* eta0_ws = ws + 16384;                // 2048 floats
  float* table = ws + 16384 + 2048;           // 34000 floats
  int* flags = (int*)(ws + 16384 + 2048 + 34000);  // (16+1)*32 ints, line-padded

  hipMemsetAsync(flags, 0, (TDONE_IDX + 1) * FLAG_STRIDE * sizeof(int), stream);
  k_fused<<<dim3(B_ + 4 + 512), dim3(256), 0, stream>>>(
      sent, em_mu, em_cho, tr_mu, tr_cho, dec_mu, dec_cho,
      lam0_ws, eta0_ws, table, flags, out);
}

// Round 8
// 67.727 us; speedup vs baseline: 1.1709x; 1.0016x over previous
//
#include <hip/hip_runtime.h>
#include <math.h>

#define B_ 4
#define T_ 64
#define D_ 8
#define V_ 2000
#define LOG2PI_F 1.8378770664093453f
#define CHUNK 16
#define NCHUNK (T_ / CHUNK)
#define FLAG_STRIDE 32                 /* one flag per 128B line */
#define TDONE_IDX 16                   /* flags[16*32] = table-done counter */

#define RCP(x) __builtin_amdgcn_rcpf(x)

__device__ __forceinline__ float rdl(float v, int lane) {
  return __int_as_float(__builtin_amdgcn_readlane(__float_as_int(v), lane));
}

// Cholesky of (A + diag(dadd)) with A read from LDS (broadcast, saves VGPRs).
__device__ __forceinline__ float chol_quad_lds(const float* sA, const float dadd[D_],
                                               const float eta[D_], float& logdet) {
  float L[D_][D_];
  float rs[D_];
  float p0 = 1.f, p1 = 1.f;
#pragma unroll
  for (int j = 0; j < D_; ++j) {
    float c = sA[j * 8 + j] + dadd[j];
#pragma unroll
    for (int k = 0; k < D_; ++k) {
      if (k < j) c -= L[j][k] * L[j][k];
    }
    if (j < 4) p0 *= c; else p1 *= c;
    float r = rsqrtf(c);
    rs[j] = r;
#pragma unroll
    for (int i = 0; i < D_; ++i) {
      if (i > j) {
        float s = sA[i * 8 + j];
#pragma unroll
        for (int k = 0; k < D_; ++k) {
          if (k < j) s -= L[i][k] * L[j][k];
        }
        L[i][j] = s * r;
      }
    }
  }
  logdet = __logf(p0) + __logf(p1);
  float z[D_];
  float q = 0.f;
#pragma unroll
  for (int i = 0; i < D_; ++i) {
    float s = eta[i];
#pragma unroll
    for (int k = 0; k < D_; ++k) {
      if (k < i) s -= L[i][k] * z[k];
    }
    z[i] = s * rs[i];
    q = fmaf(z[i], z[i], q);
  }
  return q;
}

// Fused kernel, 520 blocks:
//  blocks 0..3   : per-batch scan at WAVE PRIORITY 3 (critical serial chain);
//                  2x2-block forward (Schur) elimination; publishes every CHUNK
//                  steps (fence + relaxed store, line-padded flag)
//  blocks 4..7   : decoder table + TDONE counter (prio 0)
//  blocks 8..519 : consumers at prio 0; relaxed atomic-load polls + s_sleep
extern "C" __global__ void __launch_bounds__(256)
k_fused(const int* __restrict__ sent, const float* __restrict__ em_mu,
        const float* __restrict__ em_cho, const float* __restrict__ tr_mu,
        const float* __restrict__ tr_cho, const float* __restrict__ dec_mu,
        const float* __restrict__ dec_cho, float* __restrict__ lam0_ws,
        float* __restrict__ eta0_ws, float* __restrict__ table,
        int* __restrict__ flags, float* __restrict__ out) {
  const int bid = blockIdx.x;
  const int tid = threadIdx.x;

  if (bid < B_) {
    // ================= scan block =================
    __shared__ float sC[16][16], sCi[16][16], sLt[16][16];
    __shared__ float sEt[16], sMu[16];
    __shared__ float sLamW[T_][8], sWmuT[T_][8];
    const int b = bid;

    if (tid < 64) {
      const int sw = sent[b * T_ + tid];
      const float4* pc = (const float4*)(em_cho + sw * D_);
      const float4* pm = (const float4*)(em_mu + sw * D_);
      float4 c0 = pc[0], c1 = pc[1];
      float4 m0 = pm[0], m1 = pm[1];
      sLamW[tid][0] = RCP(c0.x * c0.x);
      sLamW[tid][1] = RCP(c0.y * c0.y);
      sLamW[tid][2] = RCP(c0.z * c0.z);
      sLamW[tid][3] = RCP(c0.w * c0.w);
      sLamW[tid][4] = RCP(c1.x * c1.x);
      sLamW[tid][5] = RCP(c1.y * c1.y);
      sLamW[tid][6] = RCP(c1.z * c1.z);
      sLamW[tid][7] = RCP(c1.w * c1.w);
      sWmuT[tid][0] = m0.x; sWmuT[tid][1] = m0.y;
      sWmuT[tid][2] = m0.z; sWmuT[tid][3] = m0.w;
      sWmuT[tid][4] = m1.x; sWmuT[tid][5] = m1.y;
      sWmuT[tid][6] = m1.z; sWmuT[tid][7] = m1.w;
    }

    // preamble: lam_t = inv(C^T C), eta_t = lam_t @ mu
    sC[tid >> 4][tid & 15] = tr_cho[tid];
    if (tid < 16) sMu[tid] = tr_mu[tid];
    __syncthreads();
    if (tid < 16) {
      const int j = tid;
      float col[16];
#pragma unroll
      for (int i = 0; i < 16; ++i) {
        float s = (i == j) ? 1.f : 0.f;
#pragma unroll
        for (int k = 0; k < 16; ++k) {
          if (k < i) s = fmaf(-sC[i][k], col[k], s);
        }
        col[i] = s * RCP(sC[i][i]);
      }
#pragma unroll
      for (int i = 0; i < 16; ++i) sCi[i][j] = col[i];
    }
    __syncthreads();
    {
      int i = tid >> 4, jq = tid & 15;
      float s = 0.f;
#pragma unroll
      for (int k = 0; k < 16; ++k) s = fmaf(sCi[i][k], sCi[jq][k], s);
      sLt[i][jq] = s;
    }
    __syncthreads();
    if (tid < 16) {
      float s = 0.f;
#pragma unroll
      for (int k = 0; k < 16; ++k) s = fmaf(sLt[tid][k], sMu[k], s);
      sEt[tid] = s;
    }
    __syncthreads();
    if (tid >= 64) return;  // wave 0 only from here; no more barriers

    __builtin_amdgcn_s_setprio(3);  // critical serial chain: win SIMD arbitration

    const int i = tid & 7;
    float ltAA[8], ltAB[8], ltBA[8], ltBB[8];
#pragma unroll
    for (int j = 0; j < 8; ++j) {
      ltAA[j] = sLt[i][j];
      ltAB[j] = sLt[i][8 + j];
      ltBA[j] = sLt[8 + i][j];
      ltBB[j] = sLt[8 + i][8 + j];
    }
    const float etH = sEt[i], etT = sEt[8 + i];

    float lam[8];
#pragma unroll
    for (int j = 0; j < 8; ++j) lam[j] = (j == i) ? 1.f : 0.f;
    float eta = 0.f;

    float* lamOut = lam0_ws + b * T_ * 64;
    float* etaOut = eta0_ws + b * T_ * 8;

    float lamw = sLamW[0][i];
    float wmu = sWmuT[0][i];

#pragma unroll 1
    for (int t = 0; t < T_; ++t) {
      float lamw_n = sLamW[(t + 1) & (T_ - 1)][i];
      float wmu_n = sWmuT[(t + 1) & (T_ - 1)][i];

      float A[8], Bm[8], Cr[8], Dm[8];
#pragma unroll
      for (int j = 0; j < 8; ++j) {
        A[j] = ltAA[j] + lam[j];
        Bm[j] = ltAB[j];
        Cr[j] = ltBA[j];
        Dm[j] = ltBB[j];
      }
      float ev = etH + eta;
      float et = etT;

      // 2x2-block forward elimination: 4 rounds, Schur lands in Dm/et.
#pragma unroll
      for (int kk = 0; kk < 8; kk += 2) {
        const int k1 = kk, k2 = kk + 1;
        float sA1[8], sA2[8], sB1[8], sB2[8];
#pragma unroll
        for (int j = 0; j < 8; ++j) {
          if (j >= k1) {
            sA1[j] = rdl(A[j], k1);
            sA2[j] = rdl(A[j], k2);
          }
        }
#pragma unroll
        for (int j = 0; j < 8; ++j) {
          sB1[j] = rdl(Bm[j], k1);
          sB2[j] = rdl(Bm[j], k2);
        }
        float sE1 = rdl(ev, k1), sE2 = rdl(ev, k2);
        float p11 = sA1[k1], p12 = sA1[k2];
        float p21 = sA2[k1], p22 = sA2[k2];
        float rdet = RCP(fmaf(p11, p22, -(p12 * p21)));
        float a1 = A[k1], a2 = A[k2];
        float g1 = (i > k2) ? (a1 * p22 - a2 * p21) * rdet : 0.f;
        float g2 = (i > k2) ? (a2 * p11 - a1 * p12) * rdet : 0.f;
        float c1 = Cr[k1], c2 = Cr[k2];
        float h1 = (c1 * p22 - c2 * p21) * rdet;
        float h2 = (c2 * p11 - c1 * p12) * rdet;
#pragma unroll
        for (int j = 0; j < 8; ++j) {
          if (j >= kk + 2) {
            A[j] = fmaf(-g1, sA1[j], fmaf(-g2, sA2[j], A[j]));
            Cr[j] = fmaf(-h1, sA1[j], fmaf(-h2, sA2[j], Cr[j]));
          }
        }
#pragma unroll
        for (int j = 0; j < 8; ++j) {
          Bm[j] = fmaf(-g1, sB1[j], fmaf(-g2, sB2[j], Bm[j]));
          Dm[j] = fmaf(-h1, sB1[j], fmaf(-h2, sB2[j], Dm[j]));
        }
        ev = fmaf(-g1, sE1, fmaf(-g2, sE2, ev));
        et = fmaf(-h1, sE1, fmaf(-h2, sE2, et));
      }

      // epilogue: lam2 = Schur + diag(lamw); eta2 = et + lamw*wmu
#pragma unroll
      for (int j = 0; j < 8; ++j) lam[j] = (j == i) ? Dm[j] + lamw : Dm[j];
      eta = fmaf(lamw, wmu, et);

      if (tid < 8) {
        float4* dst = (float4*)(lamOut + t * 64 + i * 8);
        dst[0] = make_float4(lam[0], lam[1], lam[2], lam[3]);
        dst[1] = make_float4(lam[4], lam[5], lam[6], lam[7]);
        etaOut[t * 8 + i] = eta;
      }
      if ((t & (CHUNK - 1)) == (CHUNK - 1)) {
        __threadfence();  // release: drain wave's stores to device scope
        if (tid == 0)
          __hip_atomic_store(&flags[(b * NCHUNK + (t >> 4)) * FLAG_STRIDE], 1,
                             __ATOMIC_RELAXED, __HIP_MEMORY_SCOPE_AGENT);
      }
      lamw = lamw_n;
      wmu = wmu_n;
    }
    __builtin_amdgcn_s_setprio(0);
    return;
  }

  if (bid < B_ + 4) {
    // ================= table block =================
    const int v0 = (bid - B_) * 500;
#pragma unroll
    for (int it = 0; it < 2; ++it) {
      int off = it * 256 + tid;
      if (off < 500) {
        int v = v0 + off;
        float sl = 0.f, q = 0.f;
#pragma unroll
        for (int j = 0; j < D_; ++j) {
          float c = dec_cho[v * D_ + j];
          float m = dec_mu[v * D_ + j];
          float l = 1.f / (c * c);
          float e = m * l;
          sl += __logf(l);
          q = fmaf(e, m, q);
          table[j * V_ + v] = l;
          table[(D_ + j) * V_ + v] = e;
        }
        table[16 * V_ + v] = -0.5f * (8.f * LOG2PI_F - sl + q);
      }
    }
    __threadfence();
    __syncthreads();
    if (tid == 0) atomicAdd(&flags[TDONE_IDX * FLAG_STRIDE], 1);
    return;
  }

  // ================= consumer block =================
  {
    const int cid = bid - B_ - 4;          // 0..511
    const int bt = cid >> 1;               // 0..255  (= b*64 + t)
    const int half = cid & 1;
    const int fi = (bt >> 6) * NCHUNK + ((bt & 63) >> 4);

    if (tid == 0) {
      const int* fch = &flags[fi * FLAG_STRIDE];
      while (__hip_atomic_load(fch, __ATOMIC_RELAXED, __HIP_MEMORY_SCOPE_AGENT) == 0)
        __builtin_amdgcn_s_sleep(7);
      const int* ftd = &flags[TDONE_IDX * FLAG_STRIDE];
      while (__hip_atomic_load(ftd, __ATOMIC_RELAXED, __HIP_MEMORY_SCOPE_AGENT) < 4)
        __builtin_amdgcn_s_sleep(7);
      __threadfence();  // acquire
    }
    __syncthreads();

    __shared__ float sL[64];
    __shared__ float sE[8];
    if (tid < 64) sL[tid] = lam0_ws[bt * 64 + tid];
    if (tid < 8) sE[tid] = eta0_ws[bt * 8 + tid];
    __syncthreads();

    float e0[D_];
#pragma unroll
    for (int ii = 0; ii < D_; ++ii) e0[ii] = sE[ii];
    float zero[D_];
#pragma unroll
    for (int j = 0; j < D_; ++j) zero[j] = 0.f;
    float ld0;
    float q0 = chol_quad_lds(sL, zero, e0, ld0);
    const float zeta0 = -0.5f * (8.f * LOG2PI_F - ld0 + q0);

#pragma unroll 1
    for (int it = 0; it < 4; ++it) {
      int off = it * 256 + tid;
      if (off < 1000) {
        int v = half * 1000 + off;
        float dl[D_], ef[D_];
#pragma unroll
        for (int j = 0; j < D_; ++j) {
          dl[j] = table[j * V_ + v];
          ef[j] = e0[j] + table[(D_ + j) * V_ + v];
        }
        float z1 = table[16 * V_ + v];
        float ldn;
        float qn = chol_quad_lds(sL, dl, ef, ldn);
        float zeta_n = -0.5f * (8.f * LOG2PI_F - ldn + qn);
        out[bt * V_ + v] = zeta0 + z1 - zeta_n;
      }
    }
  }
}

extern "C" void kernel_launch(void* const* d_in, const int* in_sizes, int n_in,
                              void* d_out, int out_size, void* d_ws, size_t ws_size,
                              hipStream_t stream) {
  const int* sent = (const int*)d_in[0];
  const float* em_mu = (const float*)d_in[2];
  const float* em_cho = (const float*)d_in[3];
  const float* tr_mu = (const float*)d_in[4];
  const float* tr_cho = (const float*)d_in[5];
  const float* dec_mu = (const float*)d_in[6];
  const float* dec_cho = (const float*)d_in[7];
  float* out = (float*)d_out;

  float* ws = (float*)d_ws;
  float* lam0_ws = ws;                        // 16384 floats
  float* eta0_ws = ws + 16384;                // 2048 floats
  float* table = ws + 16384 + 2048;           // 34000 floats
  int* flags = (int*)(ws + 16384 + 2048 + 34000);  // (16+1)*32 ints, line-padded

  hipMemsetAsync(flags, 0, (TDONE_IDX + 1) * FLAG_STRIDE * sizeof(int), stream);
  k_fused<<<dim3(B_ + 4 + 512), dim3(256), 0, stream>>>(
      sent, em_mu, em_cho, tr_mu, tr_cho, dec_mu, dec_cho,
      lam0_ws, eta0_ws, table, flags, out);
}

// Round 9
// 55.261 us; speedup vs baseline: 1.4351x; 1.2256x over previous
//
#include <hip/hip_runtime.h>
#include <math.h>

#define B_ 4
#define T_ 64
#define D_ 8
#define V_ 2000
#define LOG2PI_F 1.8378770664093453f
#define SEG 8                      /* steps per published segment */
#define NSEG (T_ / SEG)            /* 8 segments per batch */
#define WARM 24                    /* speculative warmup steps */
#define FLAG_STRIDE 32             /* one flag per 128B line */
#define TDONE_IDX (B_ * NSEG)      /* flags[32*32] = table-done counter */
#define NSCAN (B_ * NSEG)          /* 32 scan blocks */
#define NCONS 1024

#define RCP(x) __builtin_amdgcn_rcpf(x)

__device__ __forceinline__ float rdl(float v, int lane) {
  return __int_as_float(__builtin_amdgcn_readlane(__float_as_int(v), lane));
}

// Cholesky of (A + diag(dadd)) with A read from LDS (broadcast, saves VGPRs).
__device__ __forceinline__ float chol_quad_lds(const float* sA, const float dadd[D_],
                                               const float eta[D_], float& logdet) {
  float L[D_][D_];
  float rs[D_];
  float p0 = 1.f, p1 = 1.f;
#pragma unroll
  for (int j = 0; j < D_; ++j) {
    float c = sA[j * 8 + j] + dadd[j];
#pragma unroll
    for (int k = 0; k < D_; ++k) {
      if (k < j) c -= L[j][k] * L[j][k];
    }
    if (j < 4) p0 *= c; else p1 *= c;
    float r = rsqrtf(c);
    rs[j] = r;
#pragma unroll
    for (int i = 0; i < D_; ++i) {
      if (i > j) {
        float s = sA[i * 8 + j];
#pragma unroll
        for (int k = 0; k < D_; ++k) {
          if (k < j) s -= L[i][k] * L[j][k];
        }
        L[i][j] = s * r;
      }
    }
  }
  logdet = __logf(p0) + __logf(p1);
  float z[D_];
  float q = 0.f;
#pragma unroll
  for (int i = 0; i < D_; ++i) {
    float s = eta[i];
#pragma unroll
    for (int k = 0; k < D_; ++k) {
      if (k < i) s -= L[i][k] * z[k];
    }
    z[i] = s * rs[i];
    q = fmaf(z[i], z[i], q);
  }
  return q;
}

// blocks 0..31   : speculative scan segments: (b = bid>>3, s = bid&7).
//                  Segment s publishes steps [8s, 8s+8); segments >=3 warm up
//                  24 steps from the neutral init (filter forgetting).
// blocks 32..35  : decoder table + TDONE counter
// blocks 36..1059: consumers (500 cells each); relaxed-load polls + s_sleep
extern "C" __global__ void __launch_bounds__(256)
k_fused(const int* __restrict__ sent, const float* __restrict__ em_mu,
        const float* __restrict__ em_cho, const float* __restrict__ tr_mu,
        const float* __restrict__ tr_cho, const float* __restrict__ dec_mu,
        const float* __restrict__ dec_cho, float* __restrict__ lam0_ws,
        float* __restrict__ eta0_ws, float* __restrict__ table,
        int* __restrict__ flags, float* __restrict__ out) {
  const int bid = blockIdx.x;
  const int tid = threadIdx.x;

  if (bid < NSCAN) {
    // ================= scan segment block =================
    __shared__ float sC[16][16], sCi[16][16], sLt[16][16];
    __shared__ float sEt[16], sMu[16];
    __shared__ float sLamW[32][8], sWmuT[32][8];
    const int b = bid >> 3;
    const int s = bid & (NSEG - 1);
    const int t_end = s * SEG + SEG;
    const int t_start = (s >= 3) ? (s * SEG - WARM) : 0;
    const int nsteps = t_end - t_start;   // 8,16,24,32,...,32

    if (tid < nsteps) {
      const int swd = sent[b * T_ + t_start + tid];
      const float4* pc = (const float4*)(em_cho + swd * D_);
      const float4* pm = (const float4*)(em_mu + swd * D_);
      float4 c0 = pc[0], c1 = pc[1];
      float4 m0 = pm[0], m1 = pm[1];
      sLamW[tid][0] = RCP(c0.x * c0.x);
      sLamW[tid][1] = RCP(c0.y * c0.y);
      sLamW[tid][2] = RCP(c0.z * c0.z);
      sLamW[tid][3] = RCP(c0.w * c0.w);
      sLamW[tid][4] = RCP(c1.x * c1.x);
      sLamW[tid][5] = RCP(c1.y * c1.y);
      sLamW[tid][6] = RCP(c1.z * c1.z);
      sLamW[tid][7] = RCP(c1.w * c1.w);
      sWmuT[tid][0] = m0.x; sWmuT[tid][1] = m0.y;
      sWmuT[tid][2] = m0.z; sWmuT[tid][3] = m0.w;
      sWmuT[tid][4] = m1.x; sWmuT[tid][5] = m1.y;
      sWmuT[tid][6] = m1.z; sWmuT[tid][7] = m1.w;
    }

    // preamble: lam_t = inv(C^T C), eta_t = lam_t @ mu
    sC[tid >> 4][tid & 15] = tr_cho[tid];
    if (tid < 16) sMu[tid] = tr_mu[tid];
    __syncthreads();
    if (tid < 16) {
      const int j = tid;
      float col[16];
#pragma unroll
      for (int i = 0; i < 16; ++i) {
        float v = (i == j) ? 1.f : 0.f;
#pragma unroll
        for (int k = 0; k < 16; ++k) {
          if (k < i) v = fmaf(-sC[i][k], col[k], v);
        }
        col[i] = v * RCP(sC[i][i]);
      }
#pragma unroll
      for (int i = 0; i < 16; ++i) sCi[i][j] = col[i];
    }
    __syncthreads();
    {
      int i = tid >> 4, jq = tid & 15;
      float v = 0.f;
#pragma unroll
      for (int k = 0; k < 16; ++k) v = fmaf(sCi[i][k], sCi[jq][k], v);
      sLt[i][jq] = v;
    }
    __syncthreads();
    if (tid < 16) {
      float v = 0.f;
#pragma unroll
      for (int k = 0; k < 16; ++k) v = fmaf(sLt[tid][k], sMu[k], v);
      sEt[tid] = v;
    }
    __syncthreads();
    if (tid >= 64) return;  // wave 0 only from here; no more barriers

    const int i = tid & 7;
    float ltAA[8], ltAB[8], ltBA[8], ltBB[8];
#pragma unroll
    for (int j = 0; j < 8; ++j) {
      ltAA[j] = sLt[i][j];
      ltAB[j] = sLt[i][8 + j];
      ltBA[j] = sLt[8 + i][j];
      ltBB[j] = sLt[8 + i][8 + j];
    }
    const float etH = sEt[i], etT = sEt[8 + i];

    float lam[8];
#pragma unroll
    for (int j = 0; j < 8; ++j) lam[j] = (j == i) ? 1.f : 0.f;
    float eta = 0.f;

    float* lamOut = lam0_ws + b * T_ * 64;
    float* etaOut = eta0_ws + b * T_ * 8;

    float lamw = sLamW[0][i];
    float wmu = sWmuT[0][i];

#pragma unroll 1
    for (int tl = 0; tl < nsteps; ++tl) {
      float lamw_n = sLamW[(tl + 1) & 31][i];
      float wmu_n = sWmuT[(tl + 1) & 31][i];

      float A[8], Bm[8], Cr[8], Dm[8];
#pragma unroll
      for (int j = 0; j < 8; ++j) {
        A[j] = ltAA[j] + lam[j];
        Bm[j] = ltAB[j];
        Cr[j] = ltBA[j];
        Dm[j] = ltBB[j];
      }
      float ev = etH + eta;
      float et = etT;

      // 2x2-block forward elimination: 4 rounds, Schur lands in Dm/et.
#pragma unroll
      for (int kk = 0; kk < 8; kk += 2) {
        const int k1 = kk, k2 = kk + 1;
        float sA1[8], sA2[8], sB1[8], sB2[8];
#pragma unroll
        for (int j = 0; j < 8; ++j) {
          if (j >= k1) {
            sA1[j] = rdl(A[j], k1);
            sA2[j] = rdl(A[j], k2);
          }
        }
#pragma unroll
        for (int j = 0; j < 8; ++j) {
          sB1[j] = rdl(Bm[j], k1);
          sB2[j] = rdl(Bm[j], k2);
        }
        float sE1 = rdl(ev, k1), sE2 = rdl(ev, k2);
        float p11 = sA1[k1], p12 = sA1[k2];
        float p21 = sA2[k1], p22 = sA2[k2];
        float rdet = RCP(fmaf(p11, p22, -(p12 * p21)));
        float a1 = A[k1], a2 = A[k2];
        float g1 = (i > k2) ? (a1 * p22 - a2 * p21) * rdet : 0.f;
        float g2 = (i > k2) ? (a2 * p11 - a1 * p12) * rdet : 0.f;
        float c1 = Cr[k1], c2 = Cr[k2];
        float h1 = (c1 * p22 - c2 * p21) * rdet;
        float h2 = (c2 * p11 - c1 * p12) * rdet;
#pragma unroll
        for (int j = 0; j < 8; ++j) {
          if (j >= kk + 2) {
            A[j] = fmaf(-g1, sA1[j], fmaf(-g2, sA2[j], A[j]));
            Cr[j] = fmaf(-h1, sA1[j], fmaf(-h2, sA2[j], Cr[j]));
          }
        }
#pragma unroll
        for (int j = 0; j < 8; ++j) {
          Bm[j] = fmaf(-g1, sB1[j], fmaf(-g2, sB2[j], Bm[j]));
          Dm[j] = fmaf(-h1, sB1[j], fmaf(-h2, sB2[j], Dm[j]));
        }
        ev = fmaf(-g1, sE1, fmaf(-g2, sE2, ev));
        et = fmaf(-h1, sE1, fmaf(-h2, sE2, et));
      }

      // epilogue: lam2 = Schur + diag(lamw); eta2 = et + lamw*wmu
#pragma unroll
      for (int j = 0; j < 8; ++j) lam[j] = (j == i) ? Dm[j] + lamw : Dm[j];
      eta = fmaf(lamw, wmu, et);

      const int t = t_start + tl;
      if (t >= s * SEG && tid < 8) {
        float4* dst = (float4*)(lamOut + t * 64 + i * 8);
        dst[0] = make_float4(lam[0], lam[1], lam[2], lam[3]);
        dst[1] = make_float4(lam[4], lam[5], lam[6], lam[7]);
        etaOut[t * 8 + i] = eta;
      }
      if (tl == nsteps - 1) {
        __threadfence();  // release
        if (tid == 0)
          __hip_atomic_store(&flags[(b * NSEG + s) * FLAG_STRIDE], 1,
                             __ATOMIC_RELAXED, __HIP_MEMORY_SCOPE_AGENT);
      }
      lamw = lamw_n;
      wmu = wmu_n;
    }
    return;
  }

  if (bid < NSCAN + 4) {
    // ================= table block =================
    const int v0 = (bid - NSCAN) * 500;
#pragma unroll
    for (int it = 0; it < 2; ++it) {
      int off = it * 256 + tid;
      if (off < 500) {
        int v = v0 + off;
        float sl = 0.f, q = 0.f;
#pragma unroll
        for (int j = 0; j < D_; ++j) {
          float c = dec_cho[v * D_ + j];
          float m = dec_mu[v * D_ + j];
          float l = 1.f / (c * c);
          float e = m * l;
          sl += __logf(l);
          q = fmaf(e, m, q);
          table[j * V_ + v] = l;
          table[(D_ + j) * V_ + v] = e;
        }
        table[16 * V_ + v] = -0.5f * (8.f * LOG2PI_F - sl + q);
      }
    }
    __threadfence();
    __syncthreads();
    if (tid == 0) atomicAdd(&flags[TDONE_IDX * FLAG_STRIDE], 1);
    return;
  }

  // ================= consumer block =================
  {
    const int cid = bid - NSCAN - 4;       // 0..1023
    const int bt = cid >> 2;               // 0..255  (= b*64 + t)
    const int quarter = cid & 3;
    const int fi = (bt >> 6) * NSEG + ((bt & 63) >> 3);

    if (tid == 0) {
      const int* fch = &flags[fi * FLAG_STRIDE];
      while (__hip_atomic_load(fch, __ATOMIC_RELAXED, __HIP_MEMORY_SCOPE_AGENT) == 0)
        __builtin_amdgcn_s_sleep(7);
      const int* ftd = &flags[TDONE_IDX * FLAG_STRIDE];
      while (__hip_atomic_load(ftd, __ATOMIC_RELAXED, __HIP_MEMORY_SCOPE_AGENT) < 4)
        __builtin_amdgcn_s_sleep(7);
      __threadfence();  // acquire
    }
    __syncthreads();

    __shared__ float sL[64];
    __shared__ float sE[8];
    if (tid < 64) sL[tid] = lam0_ws[bt * 64 + tid];
    if (tid < 8) sE[tid] = eta0_ws[bt * 8 + tid];
    __syncthreads();

    float e0[D_];
#pragma unroll
    for (int ii = 0; ii < D_; ++ii) e0[ii] = sE[ii];
    float zero[D_];
#pragma unroll
    for (int j = 0; j < D_; ++j) zero[j] = 0.f;
    float ld0;
    float q0 = chol_quad_lds(sL, zero, e0, ld0);
    const float zeta0 = -0.5f * (8.f * LOG2PI_F - ld0 + q0);

#pragma unroll 1
    for (int it = 0; it < 2; ++it) {
      int off = it * 256 + tid;
      if (off < 500) {
        int v = quarter * 500 + off;
        float dl[D_], ef[D_];
#pragma unroll
        for (int j = 0; j < D_; ++j) {
          dl[j] = table[j * V_ + v];
          ef[j] = e0[j] + table[(D_ + j) * V_ + v];
        }
        float z1 = table[16 * V_ + v];
        float ldn;
        float qn = chol_quad_lds(sL, dl, ef, ldn);
        float zeta_n = -0.5f * (8.f * LOG2PI_F - ldn + qn);
        out[bt * V_ + v] = zeta0 + z1 - zeta_n;
      }
    }
  }
}

extern "C" void kernel_launch(void* const* d_in, const int* in_sizes, int n_in,
                              void* d_out, int out_size, void* d_ws, size_t ws_size,
                              hipStream_t stream) {
  const int* sent = (const int*)d_in[0];
  const float* em_mu = (const float*)d_in[2];
  const float* em_cho = (const float*)d_in[3];
  const float* tr_mu = (const float*)d_in[4];
  const float* tr_cho = (const float*)d_in[5];
  const float* dec_mu = (const float*)d_in[6];
  const float* dec_cho = (const float*)d_in[7];
  float* out = (float*)d_out;

  float* ws = (float*)d_ws;
  float* lam0_ws = ws;                        // 16384 floats
  float* eta0_ws = ws + 16384;                // 2048 floats
  float* table = ws + 16384 + 2048;           // 34000 floats
  int* flags = (int*)(ws + 16384 + 2048 + 34000);  // (32+1)*32 ints, line-padded

  hipMemsetAsync(flags, 0, (TDONE_IDX + 1) * FLAG_STRIDE * sizeof(int), stream);
  k_fused<<<dim3(NSCAN + 4 + NCONS), dim3(256), 0, stream>>>(
      sent, em_mu, em_cho, tr_mu, tr_cho, dec_mu, dec_cho,
      lam0_ws, eta0_ws, table, flags, out);
}